// Round 3
// baseline (262.592 us; speedup 1.0000x reference)
//
#include <hip/hip_runtime.h>
#include <hip/hip_bf16.h>
#include <stdint.h>

// Problem dims (fixed): B=4, S=2048, IN=1024, OUT=4096 -> M=8192, K=1024, N=4096
#define M_DIM 8192
#define K_DIM 1024
#define N_DIM 4096

typedef __bf16 bf16x8 __attribute__((ext_vector_type(8)));
typedef float  f32x4  __attribute__((ext_vector_type(4)));

__device__ __forceinline__ uint16_t f2bf(float f) {
  union { float f; uint32_t u; } x; x.f = f;
  uint32_t u = x.u;
  return (uint16_t)((u + 0x7FFFu + ((u >> 16) & 1u)) >> 16);  // RNE
}

// ---------------- kernel 1: input fp32 -> bf16 ----------------
__global__ __launch_bounds__(256) void convert_bf16_kernel(
    const float* __restrict__ in, uint16_t* __restrict__ out, int n4) {
  int i = blockIdx.x * 256 + threadIdx.x;
  if (i >= n4) return;
  float4 v = ((const float4*)in)[i];
  ushort4 o;
  o.x = f2bf(v.x); o.y = f2bf(v.y); o.z = f2bf(v.z); o.w = f2bf(v.w);
  ((ushort4*)out)[i] = o;
}

// ---------------- kernel 2: fold everything into W5^T (N x K) bf16 ----------------
// Unchanged from the verified kernel (absmax 0.0156).
__global__ __launch_bounds__(256) void build_w_kernel(
    const float* __restrict__ weight,      // (4096, 1024)
    const float* __restrict__ mask,        // (4096, 1024)
    const float* __restrict__ in_scores,   // (512)
    const float* __restrict__ out_scores,  // (2048)
    const int*   __restrict__ in_mapping,  // (1024)
    const int*   __restrict__ out_mapping, // (4096)
    uint16_t*    __restrict__ w5t)         // (4096, 1024) bf16: row=o, col=i
{
  __shared__ float    w0[K_DIM], w1[K_DIM];
  __shared__ uint16_t o0[K_DIM], o1[K_DIM];

  const int mo = blockIdx.x;       // out-pair [0, 2048)
  const int t  = threadIdx.x;      // [0, 256)

  const int r0 = out_mapping[2 * mo];
  const int r1 = out_mapping[2 * mo + 1];

  ((float4*)w0)[t] = ((const float4*)(weight + (size_t)r0 * K_DIM))[t];
  ((float4*)w1)[t] = ((const float4*)(weight + (size_t)r1 * K_DIM))[t];

  const float ao = out_scores[mo];
  const float so = sinf(ao), co = cosf(ao);

  __syncthreads();

#pragma unroll
  for (int s = 0; s < 2; s++) {
    const int mi = t + s * 256;
    const float ai = in_scores[mi];
    const float si = sinf(ai), ci = cosf(ai);
    const int ia0 = in_mapping[2 * mi];
    const int ia1 = in_mapping[2 * mi + 1];

    const float w00 = w0[ia0], w01 = w0[ia1];
    const float w10 = w1[ia0], w11 = w1[ia1];

    float a00 =  ci * w00 + si * w01;
    float a01 = -si * w00 + ci * w01;
    float a10 =  ci * w10 + si * w11;
    float a11 = -si * w10 + ci * w11;

    float b00 = co * a00 - so * a10;
    float b10 = co * a01 - so * a11;
    float b01 = so * a00 + co * a10;
    float b11 = so * a01 + co * a11;

    const float2 mk0 = *(const float2*)&mask[(size_t)(2 * mo) * K_DIM + 2 * mi];
    const float2 mk1 = *(const float2*)&mask[(size_t)(2 * mo + 1) * K_DIM + 2 * mi];
    b00 *= mk0.x; b10 *= mk0.y;
    b01 *= mk1.x; b11 *= mk1.y;

    float c00 =  co * b00 + so * b01;
    float c10 =  co * b10 + so * b11;
    float c01 = -so * b00 + co * b01;
    float c11 = -so * b10 + co * b11;

    o0[ia0] = f2bf(ci * c00 - si * c10);
    o0[ia1] = f2bf(si * c00 + ci * c10);
    o1[ia0] = f2bf(ci * c01 - si * c11);
    o1[ia1] = f2bf(si * c01 + ci * c11);
  }

  __syncthreads();

  ((uint2*)(w5t + (size_t)r0 * K_DIM))[t] = ((const uint2*)o0)[t];
  ((uint2*)(w5t + (size_t)r1 * K_DIM))[t] = ((const uint2*)o1)[t];
}

// ---------------- kernel 3: GEMM out = A(8192x1024) * W5(1024x4096), bf16 MFMA ----------------
// R7: R6's geometry/stage-schedule/waits kept verbatim (verified correct), with
// the two deviations from the m201 template removed:
//   (1) ONLY ONE sched_barrier(0) per phase (after lgkmcnt(0), rule #18).
//       R6's 16 sched_barrier(0)/tile pinned the schedule (m141: -42%) and
//       serialized ds_reads/VALU against the MFMA clusters.
//   (2) B-frag reads folded INTO phase 0 (12 ds_reads there) with the m201
//       partial drain lgkmcnt(8) before the barrier, instead of a serial lump
//       in the inter-tile gap.
// Safety under relaxed scheduling: any ds_read/stage hoist must cross a
// "memory"-clobber lgkmcnt(0) asm; landing just after a full drain is safe.
// Stage targets: A(t+1) -> opposite buf (readers done at t-1 end); B(t+2) ->
// current Bs buf, written only after phase-1 barriers (B reads completed at
// phase-0 lgkmcnt(0), which precedes them). vmcnt(4) at phase 3 forces
// A(t+1)+B(t+1) landed, keeps B(t+2) (4 loads) in flight. Never vmcnt(0) in
// the main loop (until the t==14 drain).

__device__ __forceinline__ void async_load16(const uint16_t* g, uint16_t* lds_wave_uniform) {
  __builtin_amdgcn_global_load_lds(
      (const __attribute__((address_space(1))) uint32_t*)g,
      (__attribute__((address_space(3))) uint32_t*)lds_wave_uniform,
      16, 0, 0);
}

__global__ __launch_bounds__(512, 2) void gemm_kernel(
    const uint16_t* __restrict__ A,   // (8192, 1024) bf16
    const uint16_t* __restrict__ BT,  // (4096, 1024) bf16 (W5^T, row=n, col=k)
    float* __restrict__ C)            // (8192, 4096) fp32
{
  __shared__ __align__(16) uint16_t As[2][2][128 * 64];  // 2buf x 2half x 16KB
  __shared__ __align__(16) uint16_t Bs[2][2][128 * 64];

  const int tid  = threadIdx.x;     // 0..511
  const int w    = tid >> 6;        // wave 0..7
  const int lane = tid & 63;
  const int quad = lane >> 4;
  const int rr   = lane & 15;
  const int wm   = w >> 2;          // 0..1  (M half of the tile: 128 rows)
  const int wn   = w & 3;           // 0..3  (N quarter: 64 cols)
  const int hA   = wm;              // A half this wave reads
  const int hB   = wn >> 1;         // B half this wave reads

  // XCD-bijective swizzle: 512 blocks, 64 per XCD, bn-fast within XCD.
  const int flat = blockIdx.y * gridDim.x + blockIdx.x;   // 0..511
  const int swz  = ((flat & 7) << 6) | (flat >> 3);
  const int bm   = swz >> 4;        // 0..31  (M tile of 256)
  const int bn   = swz & 15;        // 0..15  (N tile of 256)

  f32x4 acc[8][4] = {};

  // ---- staging source pointers (per-lane, XOR-preswizzled) ----
  // One half-tile = 128 rows x 64 k = 1024 chunks of 16B; thread handles
  // chunks {tid, tid+512}. chunk c: row=c>>3, stored k-group h=c&7 holds
  // global k-group g = h ^ (row&7).
  const uint16_t* gA[2];
  const uint16_t* gB[2];
#pragma unroll
  for (int ii = 0; ii < 2; ii++) {
    const int c   = ii * 512 + tid;
    const int row = c >> 3;                     // 0..127
    const int g   = (c & 7) ^ (row & 7);
    gA[ii] = A  + (size_t)(bm * 256 + row) * K_DIM + g * 8;
    gB[ii] = BT + (size_t)(bn * 256 + row) * K_DIM + g * 8;
  }

#define STAGE_A(BUF, H, KT)                                                   \
  do {                                                                        \
    _Pragma("unroll")                                                         \
    for (int ii_ = 0; ii_ < 2; ii_++)                                         \
      async_load16(gA[ii_] + (H) * (128 * K_DIM) + (KT) * 64,                 \
                   &As[BUF][H][(ii_ * 512 + w * 64) * 8]);                    \
  } while (0)

#define STAGE_B(BUF, H, KT)                                                   \
  do {                                                                        \
    _Pragma("unroll")                                                         \
    for (int ii_ = 0; ii_ < 2; ii_++)                                         \
      async_load16(gB[ii_] + (H) * (128 * K_DIM) + (KT) * 64,                 \
                   &Bs[BUF][H][(ii_ * 512 + w * 64) * 8]);                    \
  } while (0)

  // ---- fragment LDS offsets (within the wave's half buffer, u16 units) ----
  int offA[8][2], offB[4][2];
#pragma unroll
  for (int i = 0; i < 8; i++) {
    const int r = i * 16 + rr;                  // row within A half
#pragma unroll
    for (int s = 0; s < 2; s++) {
      const int gk = s * 4 + quad;
      offA[i][s] = (r * 8 + (gk ^ (r & 7))) * 8;
    }
  }
#pragma unroll
  for (int j = 0; j < 4; j++) {
    const int r = (wn & 1) * 64 + j * 16 + rr;  // row within B half
#pragma unroll
    for (int s = 0; s < 2; s++) {
      const int gk = s * 4 + quad;
      offB[j][s] = (r * 8 + (gk ^ (r & 7))) * 8;
    }
  }

  // Phase P: {own ds_reads (+B reads in P0) ; stage ; [waits] ; barrier ;
  // lgkmcnt(0) ; sched_barrier ; prio ; 16 MFMA ; prio ; barrier}.
  // NO other scheduling pins.
#define PHASE(P, EXTRA_READS, STAGE_STMT, PRE_BARRIER_WAITS)                   \
  {                                                                            \
    bf16x8 af[2][2];                                                           \
    EXTRA_READS;                                                               \
    _Pragma("unroll")                                                          \
    for (int d_ = 0; d_ < 2; d_++)                                             \
      _Pragma("unroll")                                                        \
      for (int s_ = 0; s_ < 2; s_++)                                           \
        af[d_][s_] = *reinterpret_cast<const bf16x8*>(asb + offA[2*(P)+d_][s_]); \
    STAGE_STMT;                                                                \
    PRE_BARRIER_WAITS;                                                         \
    __builtin_amdgcn_s_barrier();                                              \
    asm volatile("s_waitcnt lgkmcnt(0)" ::: "memory");                         \
    __builtin_amdgcn_sched_barrier(0);                                         \
    __builtin_amdgcn_s_setprio(1);                                             \
    _Pragma("unroll")                                                          \
    for (int s_ = 0; s_ < 2; s_++)                                             \
      _Pragma("unroll")                                                        \
      for (int d_ = 0; d_ < 2; d_++)                                           \
        _Pragma("unroll")                                                      \
        for (int j_ = 0; j_ < 4; j_++)                                         \
          acc[2*(P)+d_][j_] = __builtin_amdgcn_mfma_f32_16x16x32_bf16(         \
              af[d_][s_], bfv[j_][s_], acc[2*(P)+d_][j_], 0, 0, 0);            \
    __builtin_amdgcn_s_setprio(0);                                             \
    __builtin_amdgcn_s_barrier();                                              \
  }

  // ---- prologue: B(0), A(0), B(1); keep B(1)'s 4 loads in flight ----
  STAGE_B(0, 0, 0); STAGE_B(0, 1, 0);
  STAGE_A(0, 0, 0); STAGE_A(0, 1, 0);
  STAGE_B(1, 0, 1); STAGE_B(1, 1, 1);
  asm volatile("s_waitcnt vmcnt(4)" ::: "memory");   // B(0), A(0) landed
  __builtin_amdgcn_s_barrier();

  // ---- main loop: 16 K-tiles x 4 phases ----
  for (int t = 0; t < 16; ++t) {
    const int buf  = t & 1;
    const int nbuf = buf ^ 1;
    const uint16_t* asb = &As[buf][hA][0];
    const uint16_t* bsb = &Bs[buf][hB][0];

    bf16x8 bfv[4][2];

    PHASE(0,
          { _Pragma("unroll")
            for (int j_ = 0; j_ < 4; j_++)
              _Pragma("unroll")
              for (int s_ = 0; s_ < 2; s_++)
                bfv[j_][s_] = *reinterpret_cast<const bf16x8*>(bsb + offB[j_][s_]); },
          { if (t < 15) STAGE_A(nbuf, 0, t + 1); },
          { asm volatile("s_waitcnt lgkmcnt(8)" ::: "memory"); });
    PHASE(1, {}, { if (t < 15) STAGE_A(nbuf, 1, t + 1); }, {});
    PHASE(2, {}, { if (t < 14) STAGE_B(buf, 0, t + 2); }, {});
    PHASE(3, {}, { if (t < 14) STAGE_B(buf, 1, t + 2); },
          { if (t < 14)       { asm volatile("s_waitcnt vmcnt(4)" ::: "memory"); }
            else if (t == 14) { asm volatile("s_waitcnt vmcnt(0)" ::: "memory"); } });
  }

#undef PHASE
#undef STAGE_A
#undef STAGE_B

  // ---- epilogue: D layout col = lane&15 (n), row = quad*4 + reg (m) ----
#pragma unroll
  for (int i = 0; i < 8; i++) {
    const int row0 = bm * 256 + wm * 128 + i * 16 + quad * 4;
#pragma unroll
    for (int j = 0; j < 4; j++) {
      const int col = bn * 256 + wn * 64 + j * 16 + rr;
#pragma unroll
      for (int rg = 0; rg < 4; rg++) {
        C[(size_t)(row0 + rg) * N_DIM + col] = acc[i][j][rg];
      }
    }
  }
}

extern "C" void kernel_launch(void* const* d_in, const int* in_sizes, int n_in,
                              void* d_out, int out_size, void* d_ws, size_t ws_size,
                              hipStream_t stream) {
  const float* input      = (const float*)d_in[0];
  const float* weight     = (const float*)d_in[1];
  const float* mask       = (const float*)d_in[2];
  const float* in_scores  = (const float*)d_in[3];
  const float* out_scores = (const float*)d_in[4];
  const int*   in_mapping = (const int*)d_in[5];
  const int*   out_mapping= (const int*)d_in[6];
  // d_in[7] = out_mapping_reverse (folded away), d_in[8] = temperature (unused)
  float* out = (float*)d_out;

  uint16_t* a_bf16 = (uint16_t*)d_ws;                              // 8192*1024 bf16 = 16 MB
  uint16_t* w5t    = (uint16_t*)d_ws + (size_t)M_DIM * K_DIM;      // 4096*1024 bf16 = 8 MB

  convert_bf16_kernel<<<(M_DIM * K_DIM / 4 + 255) / 256, 256, 0, stream>>>(
      input, a_bf16, M_DIM * K_DIM / 4);

  build_w_kernel<<<2048, 256, 0, stream>>>(
      weight, mask, in_scores, out_scores, in_mapping, out_mapping, w5t);

  dim3 grid(N_DIM / 256, M_DIM / 256);  // (16, 32) = 512 blocks, %8 == 0
  gemm_kernel<<<grid, 512, 0, stream>>>(a_bf16, w5t, out);
}

// Round 4
// 254.443 us; speedup vs baseline: 1.0320x; 1.0320x over previous
//
#include <hip/hip_runtime.h>
#include <hip/hip_bf16.h>
#include <stdint.h>

// Problem dims (fixed): B=4, S=2048, IN=1024, OUT=4096 -> M=8192, K=1024, N=4096
#define M_DIM 8192
#define K_DIM 1024
#define N_DIM 4096

typedef __bf16 bf16x8 __attribute__((ext_vector_type(8)));
typedef float  f32x4  __attribute__((ext_vector_type(4)));

__device__ __forceinline__ uint16_t f2bf(float f) {
  union { float f; uint32_t u; } x; x.f = f;
  uint32_t u = x.u;
  return (uint16_t)((u + 0x7FFFu + ((u >> 16) & 1u)) >> 16);  // RNE
}

// ---------------- kernel 1: input fp32 -> bf16 ----------------
__global__ __launch_bounds__(256) void convert_bf16_kernel(
    const float* __restrict__ in, uint16_t* __restrict__ out, int n4) {
  int i = blockIdx.x * 256 + threadIdx.x;
  if (i >= n4) return;
  float4 v = ((const float4*)in)[i];
  ushort4 o;
  o.x = f2bf(v.x); o.y = f2bf(v.y); o.z = f2bf(v.z); o.w = f2bf(v.w);
  ((ushort4*)out)[i] = o;
}

// ---------------- kernel 2: fold everything into W5^T (N x K) bf16 ----------------
// Unchanged from the verified kernel (absmax 0.0156).
__global__ __launch_bounds__(256) void build_w_kernel(
    const float* __restrict__ weight,      // (4096, 1024)
    const float* __restrict__ mask,        // (4096, 1024)
    const float* __restrict__ in_scores,   // (512)
    const float* __restrict__ out_scores,  // (2048)
    const int*   __restrict__ in_mapping,  // (1024)
    const int*   __restrict__ out_mapping, // (4096)
    uint16_t*    __restrict__ w5t)         // (4096, 1024) bf16: row=o, col=i
{
  __shared__ float    w0[K_DIM], w1[K_DIM];
  __shared__ uint16_t o0[K_DIM], o1[K_DIM];

  const int mo = blockIdx.x;       // out-pair [0, 2048)
  const int t  = threadIdx.x;      // [0, 256)

  const int r0 = out_mapping[2 * mo];
  const int r1 = out_mapping[2 * mo + 1];

  ((float4*)w0)[t] = ((const float4*)(weight + (size_t)r0 * K_DIM))[t];
  ((float4*)w1)[t] = ((const float4*)(weight + (size_t)r1 * K_DIM))[t];

  const float ao = out_scores[mo];
  const float so = sinf(ao), co = cosf(ao);

  __syncthreads();

#pragma unroll
  for (int s = 0; s < 2; s++) {
    const int mi = t + s * 256;
    const float ai = in_scores[mi];
    const float si = sinf(ai), ci = cosf(ai);
    const int ia0 = in_mapping[2 * mi];
    const int ia1 = in_mapping[2 * mi + 1];

    const float w00 = w0[ia0], w01 = w0[ia1];
    const float w10 = w1[ia0], w11 = w1[ia1];

    float a00 =  ci * w00 + si * w01;
    float a01 = -si * w00 + ci * w01;
    float a10 =  ci * w10 + si * w11;
    float a11 = -si * w10 + ci * w11;

    float b00 = co * a00 - so * a10;
    float b10 = co * a01 - so * a11;
    float b01 = so * a00 + co * a10;
    float b11 = so * a01 + co * a11;

    const float2 mk0 = *(const float2*)&mask[(size_t)(2 * mo) * K_DIM + 2 * mi];
    const float2 mk1 = *(const float2*)&mask[(size_t)(2 * mo + 1) * K_DIM + 2 * mi];
    b00 *= mk0.x; b10 *= mk0.y;
    b01 *= mk1.x; b11 *= mk1.y;

    float c00 =  co * b00 + so * b01;
    float c10 =  co * b10 + so * b11;
    float c01 = -so * b00 + co * b01;
    float c11 = -so * b10 + co * b11;

    o0[ia0] = f2bf(ci * c00 - si * c10);
    o0[ia1] = f2bf(si * c00 + ci * c10);
    o1[ia0] = f2bf(ci * c01 - si * c11);
    o1[ia1] = f2bf(si * c01 + ci * c11);
  }

  __syncthreads();

  ((uint2*)(w5t + (size_t)r0 * K_DIM))[t] = ((const uint2*)o0)[t];
  ((uint2*)(w5t + (size_t)r1 * K_DIM))[t] = ((const uint2*)o1)[t];
}

// ---------------- kernel 3: GEMM out = A(8192x1024) * W5(1024x4096), bf16 MFMA ----------------
// R8: same geometry/stage-schedule as R6/R7 (256x256, BK=64, 8 waves, 2buf x
// 2half LDS, counted vmcnt, raw barriers), with the missing lever added:
// ds_read || MFMA interleave. Phase P's fragments are loaded during phase
// P-1's MFMA cluster (ping-pong afA/afB; next tile's B frags + first A frags
// loaded under phase 3's MFMA). Each phase's lgkmcnt(0) then drains reads
// that had a full MFMA cluster + barrier to complete -> ~zero wait.
// The counted wait moves from p3 to p2 (vmcnt(2): drains A(t+1),B(t+1),
// leaves B0(t+2) in flight); p2's end barrier makes those stages block-wide
// visible BEFORE the p3 cross-tile prefetch reads As/Bs[nbuf]. Tails peeled:
// t=14 (no B stage, vmcnt(0)@p2), t=15 (no stages, no prefetch).

__device__ __forceinline__ void async_load16(const uint16_t* g, uint16_t* lds_wave_uniform) {
  __builtin_amdgcn_global_load_lds(
      (const __attribute__((address_space(1))) uint32_t*)g,
      (__attribute__((address_space(3))) uint32_t*)lds_wave_uniform,
      16, 0, 0);
}

__global__ __launch_bounds__(512, 2) void gemm_kernel(
    const uint16_t* __restrict__ A,   // (8192, 1024) bf16
    const uint16_t* __restrict__ BT,  // (4096, 1024) bf16 (W5^T, row=n, col=k)
    float* __restrict__ C)            // (8192, 4096) fp32
{
  __shared__ __align__(16) uint16_t As[2][2][128 * 64];  // 2buf x 2half x 16KB
  __shared__ __align__(16) uint16_t Bs[2][2][128 * 64];

  const int tid  = threadIdx.x;     // 0..511
  const int w    = tid >> 6;        // wave 0..7
  const int lane = tid & 63;
  const int quad = lane >> 4;
  const int rr   = lane & 15;
  const int wm   = w >> 2;          // 0..1  (M half of the tile: 128 rows)
  const int wn   = w & 3;           // 0..3  (N quarter: 64 cols)
  const int hA   = wm;              // A half this wave reads
  const int hB   = wn >> 1;         // B half this wave reads

  // XCD-bijective swizzle: 512 blocks, 64 per XCD, bn-fast within XCD.
  const int flat = blockIdx.y * gridDim.x + blockIdx.x;   // 0..511
  const int swz  = ((flat & 7) << 6) | (flat >> 3);
  const int bm   = swz >> 4;        // 0..31  (M tile of 256)
  const int bn   = swz & 15;        // 0..15  (N tile of 256)

  f32x4 acc[8][4] = {};

  // ---- staging source pointers (per-lane, XOR-preswizzled) ----
  const uint16_t* gA[2];
  const uint16_t* gB[2];
#pragma unroll
  for (int ii = 0; ii < 2; ii++) {
    const int c   = ii * 512 + tid;
    const int row = c >> 3;                     // 0..127
    const int g   = (c & 7) ^ (row & 7);
    gA[ii] = A  + (size_t)(bm * 256 + row) * K_DIM + g * 8;
    gB[ii] = BT + (size_t)(bn * 256 + row) * K_DIM + g * 8;
  }

#define STAGE_A(BUF, H, KT)                                                   \
  do {                                                                        \
    _Pragma("unroll")                                                         \
    for (int ii_ = 0; ii_ < 2; ii_++)                                         \
      async_load16(gA[ii_] + (H) * (128 * K_DIM) + (KT) * 64,                 \
                   &As[BUF][H][(ii_ * 512 + w * 64) * 8]);                    \
  } while (0)

#define STAGE_B(BUF, H, KT)                                                   \
  do {                                                                        \
    _Pragma("unroll")                                                         \
    for (int ii_ = 0; ii_ < 2; ii_++)                                         \
      async_load16(gB[ii_] + (H) * (128 * K_DIM) + (KT) * 64,                 \
                   &Bs[BUF][H][(ii_ * 512 + w * 64) * 8]);                    \
  } while (0)

  // ---- fragment LDS offsets (within the wave's half buffer, u16 units) ----
  int offA[8][2], offB[4][2];
#pragma unroll
  for (int i = 0; i < 8; i++) {
    const int r = i * 16 + rr;                  // row within A half
#pragma unroll
    for (int s = 0; s < 2; s++) {
      const int gk = s * 4 + quad;
      offA[i][s] = (r * 8 + (gk ^ (r & 7))) * 8;
    }
  }
#pragma unroll
  for (int j = 0; j < 4; j++) {
    const int r = (wn & 1) * 64 + j * 16 + rr;  // row within B half
#pragma unroll
    for (int s = 0; s < 2; s++) {
      const int gk = s * 4 + quad;
      offB[j][s] = (r * 8 + (gk ^ (r & 7))) * 8;
    }
  }

#define PF_A(AF, ASB, R)                                                      \
  _Pragma("unroll")                                                           \
  for (int d_ = 0; d_ < 2; d_++)                                              \
    _Pragma("unroll")                                                         \
    for (int s_ = 0; s_ < 2; s_++)                                            \
      AF[d_][s_] = *reinterpret_cast<const bf16x8*>((ASB) + offA[(R) + d_][s_]);

#define PF_B(BN, BSB)                                                         \
  _Pragma("unroll")                                                           \
  for (int j_ = 0; j_ < 4; j_++)                                              \
    _Pragma("unroll")                                                         \
    for (int s_ = 0; s_ < 2; s_++)                                            \
      BN[j_][s_] = *reinterpret_cast<const bf16x8*>((BSB) + offB[j_][s_]);

#define MFMA16(AF, R, BV)                                                     \
  _Pragma("unroll")                                                           \
  for (int s_ = 0; s_ < 2; s_++)                                              \
    _Pragma("unroll")                                                         \
    for (int d_ = 0; d_ < 2; d_++)                                            \
      _Pragma("unroll")                                                       \
      for (int j_ = 0; j_ < 4; j_++)                                          \
        acc[(R) + d_][j_] = __builtin_amdgcn_mfma_f32_16x16x32_bf16(          \
            AF[d_][s_], BV[j_][s_], acc[(R) + d_][j_], 0, 0, 0);

  // Phase: {stage ; [vm wait] ; barrier ; lgkmcnt(0) ; sched_barrier ;
  //         prio1 ; prefetch(next phase frags) + 16 MFMA ; prio0 ; barrier}
#define PHASE(STAGE_STMT, WAIT_STMT, PF_STMT, AF, RBASE, BV)                  \
  {                                                                           \
    STAGE_STMT;                                                               \
    WAIT_STMT;                                                                \
    __builtin_amdgcn_s_barrier();                                             \
    asm volatile("s_waitcnt lgkmcnt(0)" ::: "memory");                        \
    __builtin_amdgcn_sched_barrier(0);                                        \
    __builtin_amdgcn_s_setprio(1);                                            \
    PF_STMT;                                                                  \
    MFMA16(AF, RBASE, BV);                                                    \
    __builtin_amdgcn_s_setprio(0);                                            \
    __builtin_amdgcn_s_barrier();                                             \
  }

  // MODE: 0 = steady, 1 = t14 (no B stage, vmcnt(0)@p2), 2 = t15 (no stages,
  // no cross-tile prefetch). BV = this tile's B frags, BN = next tile's.
#define TILE(T, BV, BN, MODE)                                                 \
  {                                                                           \
    const int buf_ = (T) & 1;                                                 \
    const uint16_t* asb_  = &As[buf_][hA][0];                                 \
    const uint16_t* asb_n = &As[buf_ ^ 1][hA][0];                             \
    const uint16_t* bsb_n = &Bs[buf_ ^ 1][hB][0];                             \
    PHASE({ if (MODE < 2) STAGE_A(buf_ ^ 1, 0, (T) + 1); }, {},               \
          { PF_A(afB, asb_, 2) }, afA, 0, BV);                                \
    PHASE({ if (MODE < 2) STAGE_A(buf_ ^ 1, 1, (T) + 1); }, {},               \
          { PF_A(afA, asb_, 4) }, afB, 2, BV);                                \
    PHASE({ if (MODE == 0) STAGE_B(buf_, 0, (T) + 2); },                      \
          { if (MODE == 0)      { asm volatile("s_waitcnt vmcnt(2)" ::: "memory"); } \
            else if (MODE == 1) { asm volatile("s_waitcnt vmcnt(0)" ::: "memory"); } }, \
          { PF_A(afB, asb_, 6) }, afA, 4, BV);                                \
    PHASE({ if (MODE == 0) STAGE_B(buf_, 1, (T) + 2); }, {},                  \
          { if (MODE < 2) { PF_A(afA, asb_n, 0) PF_B(BN, bsb_n) } },          \
          afB, 6, BV);                                                        \
  }

  // ---- prologue: stage B(0), A(0), B(1); leave B(1) in flight ----
  STAGE_B(0, 0, 0); STAGE_B(0, 1, 0);
  STAGE_A(0, 0, 0); STAGE_A(0, 1, 0);
  STAGE_B(1, 0, 1); STAGE_B(1, 1, 1);
  asm volatile("s_waitcnt vmcnt(4)" ::: "memory");   // B(0), A(0) landed
  __builtin_amdgcn_s_barrier();                      // ... block-wide

  bf16x8 afA[2][2], afB[2][2], bfvA[4][2], bfvB[4][2];
  PF_A(afA, (&As[0][hA][0]), 0);     // tile0 p0 A frags
  PF_B(bfvA, (&Bs[0][hB][0]));       // tile0 B frags

  // ---- main loop: tiles 0..13 steady (2 per iter for B ping-pong) ----
  for (int t = 0; t < 14; t += 2) {
    TILE(t,     bfvA, bfvB, 0);
    TILE(t + 1, bfvB, bfvA, 0);
  }
  TILE(14, bfvA, bfvB, 1);
  TILE(15, bfvB, bfvB, 2);

#undef TILE
#undef PHASE
#undef MFMA16
#undef PF_A
#undef PF_B
#undef STAGE_A
#undef STAGE_B

  // ---- epilogue: D layout col = lane&15 (n), row = quad*4 + reg (m) ----
#pragma unroll
  for (int i = 0; i < 8; i++) {
    const int row0 = bm * 256 + wm * 128 + i * 16 + quad * 4;
#pragma unroll
    for (int j = 0; j < 4; j++) {
      const int col = bn * 256 + wn * 64 + j * 16 + rr;
#pragma unroll
      for (int rg = 0; rg < 4; rg++) {
        C[(size_t)(row0 + rg) * N_DIM + col] = acc[i][j][rg];
      }
    }
  }
}

extern "C" void kernel_launch(void* const* d_in, const int* in_sizes, int n_in,
                              void* d_out, int out_size, void* d_ws, size_t ws_size,
                              hipStream_t stream) {
  const float* input      = (const float*)d_in[0];
  const float* weight     = (const float*)d_in[1];
  const float* mask       = (const float*)d_in[2];
  const float* in_scores  = (const float*)d_in[3];
  const float* out_scores = (const float*)d_in[4];
  const int*   in_mapping = (const int*)d_in[5];
  const int*   out_mapping= (const int*)d_in[6];
  // d_in[7] = out_mapping_reverse (folded away), d_in[8] = temperature (unused)
  float* out = (float*)d_out;

  uint16_t* a_bf16 = (uint16_t*)d_ws;                              // 8192*1024 bf16 = 16 MB
  uint16_t* w5t    = (uint16_t*)d_ws + (size_t)M_DIM * K_DIM;      // 4096*1024 bf16 = 8 MB

  convert_bf16_kernel<<<(M_DIM * K_DIM / 4 + 255) / 256, 256, 0, stream>>>(
      input, a_bf16, M_DIM * K_DIM / 4);

  build_w_kernel<<<2048, 256, 0, stream>>>(
      weight, mask, in_scores, out_scores, in_mapping, out_mapping, w5t);

  dim3 grid(N_DIM / 256, M_DIM / 256);  // (16, 32) = 512 blocks, %8 == 0
  gemm_kernel<<<grid, 512, 0, stream>>>(a_bf16, w5t, out);
}